// Round 2
// baseline (176.753 us; speedup 1.0000x reference)
//
#include <hip/hip_runtime.h>

#define BB 8
#define SS 4096
#define DD 768
#define NN 64
#define D4 (DD / 4)        // 192 float4 columns
#define NWIN 32            // uniform 128-token windows per batch
#define WTOK 128
#define ACC_FLOATS (BB * NN * DD)   // 393216 floats per accumulator array
// ws layout: float gsum[BB][NN][DD] (1,572,864 B) then float gcnt[BB][NN][DD]
// (1,572,864 B). Both zero-initialized by zero_kernel each launch (harness
// poisons ws). Window kernel accumulates with device-scope float atomicAdd;
// ordering nondeterminism is within the 1e-3 absmax tolerance, counts are
// exact integers in f32.

// native vector type accepted by __builtin_nontemporal_load
typedef float nfloat4 __attribute__((ext_vector_type(4)));

// ---------------- Phase A: zero accumulators (3 MB, ~1 us) -----------------
__global__ __launch_bounds__(256) void zero_kernel(float4* __restrict__ ws) {
    const size_t i = (size_t)blockIdx.x * 256 + threadIdx.x;
    ws[i] = make_float4(0.f, 0.f, 0.f, 0.f);   // grid covers 2*ACC_FLOATS/4
}

// ---------------- Phase B: balanced fixed-window partials ------------------
// R14 EXPERIMENT (T_B: imbalance, not access pattern, is the 2.3 TB/s wall).
// grid: (NWIN, BB, 3) = 768 blocks = exactly 3/CU, 256 threads (4 waves).
// Every block reads exactly 128 contiguous token rows' 64-float4 column
// slice (128 KB, NT loads — R13 proved plain loads are WORSE here, revert).
// Wave w owns the 32 consecutive tokens [win*128+w*32, +32): segment ids are
// nondecreasing and wave-uniform, so boundary flushes are uniform branches.
// Partials flushed via atomicAdd into gsum/gcnt[b][seg][col].
__global__ __launch_bounds__(256) void window_kernel(
    const float* __restrict__ wv,
    const int* __restrict__ lens,
    float* __restrict__ gsum,
    float* __restrict__ gcnt)
{
    const int win  = blockIdx.x;     // 0..31
    const int b    = blockIdx.y;
    const int g    = blockIdx.z;     // colgroup 0..2
    const int tid  = threadIdx.x;
    const int lane = tid & 63;
    const int w    = tid >> 6;       // 0..3

    // inclusive scan of the 64 segment lengths -> ends[lane] in registers
    int e = lens[b * NN + lane];
    #pragma unroll
    for (int off = 1; off < 64; off <<= 1) {
        int a = __shfl_up(e, off); if (lane >= off) e += a;
    }

    const int tstart = win * WTOK + w * 32;
    const int tend   = tstart + 32;
    const int col4   = g * 64 + lane;
    const nfloat4* base = (const nfloat4*)wv + (size_t)b * SS * D4 + col4;

    // segment of first token: count of ends <= tstart (wave-uniform result)
    int seg     = __popcll(__ballot(e <= tstart));
    int cur_end = __shfl(e, seg);

    float4 s = make_float4(0.f, 0.f, 0.f, 0.f);
    float4 c = make_float4(0.f, 0.f, 0.f, 0.f);

    #define ACC(T)                                                      \
        {                                                               \
            nfloat4 v = __builtin_nontemporal_load(base + (size_t)(T) * D4); \
            s.x += v.x; s.y += v.y; s.z += v.z; s.w += v.w;             \
            c.x += (v.x != 0.f) ? 1.f : 0.f;                            \
            c.y += (v.y != 0.f) ? 1.f : 0.f;                            \
            c.z += (v.z != 0.f) ? 1.f : 0.f;                            \
            c.w += (v.w != 0.f) ? 1.f : 0.f;                            \
        }

    #define FLUSH(SG)                                                   \
        {                                                               \
            float* ps = gsum + ((size_t)(b * NN + (SG)) * D4 + col4) * 4; \
            float* pc = gcnt + ((size_t)(b * NN + (SG)) * D4 + col4) * 4; \
            atomicAdd(ps + 0, s.x); atomicAdd(ps + 1, s.y);             \
            atomicAdd(ps + 2, s.z); atomicAdd(ps + 3, s.w);             \
            atomicAdd(pc + 0, c.x); atomicAdd(pc + 1, c.y);             \
            atomicAdd(pc + 2, c.z); atomicAdd(pc + 3, c.w);             \
        }

    if (cur_end >= tend) {
        // fast path (~60%): whole 32-token run inside one segment
        #pragma unroll 8
        for (int t = tstart; t < tend; ++t) ACC(t);
        FLUSH(seg);
    } else {
        for (int t = tstart; t < tend; ++t) {
            if (t >= cur_end) {              // wave-uniform boundary
                FLUSH(seg);
                s = make_float4(0.f, 0.f, 0.f, 0.f);
                c = make_float4(0.f, 0.f, 0.f, 0.f);
                seg     = __popcll(__ballot(e <= t));
                cur_end = __shfl(e, seg);
            }
            ACC(t);
        }
        FLUSH(seg);
    }
    #undef ACC
    #undef FLUSH
}

// ---------------- Phase C: finalize (mean, fallback, rep, masks) -----------
// grid: BB*NN = 512 blocks, 256 threads (192 active cols). Direct read of
// the dense accumulators (no K-gather, no scan), then proven epilogue.
__global__ __launch_bounds__(256) void finalize_kernel(
    const float* __restrict__ wv,
    const int* __restrict__ rep_ids,
    const float* __restrict__ rep_mask,
    const float* __restrict__ len_mask,
    const float* __restrict__ gsum,
    const float* __restrict__ gcnt,
    float* __restrict__ out)
{
    __shared__ float s_part[4];
    const int sgid = blockIdx.x;          // b*NN + n
    const int b = sgid >> 6, n = sgid & 63;
    const int tid = threadIdx.x;
    const bool active = tid < D4;

    float4 S = make_float4(0,0,0,0), C = S;
    if (active) {
        S = ((const float4*)gsum)[(size_t)sgid * D4 + tid];
        C = ((const float4*)gcnt)[(size_t)sgid * D4 + tid];
    }

    float tot = C.x + C.y + C.z + C.w;    // 0 for inactive lanes
    #pragma unroll
    for (int off = 32; off; off >>= 1) tot += __shfl_xor(tot, off);
    if ((tid & 63) == 0) s_part[tid >> 6] = tot;
    __syncthreads();
    const float total = s_part[0] + s_part[1] + s_part[2] + s_part[3];

    if (active) {
        float4 mean;
        mean.x = S.x / fmaxf(C.x, 1.f);
        mean.y = S.y / fmaxf(C.y, 1.f);
        mean.z = S.z / fmaxf(C.z, 1.f);
        mean.w = S.w / fmaxf(C.w, 1.f);
        if (total == 0.f) mean = ((const float4*)wv)[tid];   // wv[0,0,:]

        const float lm = len_mask[sgid];
        mean.x *= lm; mean.y *= lm; mean.z *= lm; mean.w *= lm;

        float4* out4 = (float4*)out;
        out4[(size_t)(b * 2 * NN + NN + n) * D4 + tid] = mean;

        const int   rid = rep_ids[sgid];
        const float rm  = rep_mask[sgid];
        float4 rv = ((const float4*)wv)[(size_t)(b * SS + rid) * D4 + tid];
        rv.x *= rm; rv.y *= rm; rv.z *= rm; rv.w *= rm;
        out4[(size_t)(b * 2 * NN + n) * D4 + tid] = rv;

        if (tid == 0) {
            float* masks = out + (size_t)BB * 2 * NN * DD;
            masks[b * 2 * NN + n]      = rm;
            masks[b * 2 * NN + NN + n] = lm;
        }
    }
}

extern "C" void kernel_launch(void* const* d_in, const int* in_sizes, int n_in,
                              void* d_out, int out_size, void* d_ws, size_t ws_size,
                              hipStream_t stream) {
    const float* wv       = (const float*)d_in[0];
    const int*   rep_ids  = (const int*)d_in[1];
    const float* rep_mask = (const float*)d_in[2];
    const int*   lens     = (const int*)d_in[3];
    const float* len_mask = (const float*)d_in[4];
    float*       out      = (float*)d_out;
    float* gsum = (float*)d_ws;
    float* gcnt = (float*)d_ws + ACC_FLOATS;

    // zero 2*ACC_FLOATS floats = 196608 float4 -> 768 blocks x 256 threads
    zero_kernel<<<768, 256, 0, stream>>>((float4*)d_ws);
    window_kernel<<<dim3(NWIN, BB, 3), 256, 0, stream>>>(wv, lens, gsum, gcnt);
    finalize_kernel<<<BB * NN, 256, 0, stream>>>(wv, rep_ids, rep_mask,
                                                 len_mask, gsum, gcnt, out);
}

// Round 3
// 155.829 us; speedup vs baseline: 1.1343x; 1.1343x over previous
//
#include <hip/hip_runtime.h>

#define BB 8
#define SS 4096
#define DD 768
#define NN 64
#define D4 (DD / 4)        // 192 float4 columns
#define CHT 128            // tokens per chunk
#define MAXCH 96           // max chunks per batch: 64 + 4032/128 = 95 <= 96
#define NREC (BB * MAXCH)  // 768 chunk records
// ws layout: float sum[NREC][DD] (2,359,296 B) then u8 cnt[NREC][DD] (589,824 B)
// total 2,949,120 B <= ws_size. No zero-init: every record read by finalize
// is written by exactly one owner block.
//
// R15: exact revert to the proven 156.9us baseline (NT loads, segment-aligned
// chunks, record scheme) EXCEPT the chunk grid mapping: x = cidx*3 + g so the
// three colgroup blocks that read the SAME 128 token rows are adjacent in
// dispatch order (baseline had g in blockIdx.z -> 768 dispatch slots apart ->
// each 3KB row span fetched in 3 temporally-distant 1KB strided passes ->
// DRAM row reopened ~3x). Theory: row-activation thrash is the 2.3 TB/s wall.
// Dead theories (do not retry): per-block access pattern (R11), LDS-DMA (R12),
// plain/cached loads (R13, +9us), balanced windows + atomics (R14, +20us).

// native vector type accepted by __builtin_nontemporal_load (float4 is a
// HIP_vector_type class, which the builtin rejects; this is layout-identical)
typedef float nfloat4 __attribute__((ext_vector_type(4)));

// ---------------- Phase B: balanced chunk partials, NO atomics --------------
// grid: (3*MAXCH, BB), block 256 (4 waves). Block (x=cidx*3+g, b) locates its
// chunk (<=128 tokens, wholly inside one segment) via wave scans, streams
// tokens stride-4-waves reading float4 col g*64+lane with NON-TEMPORAL loads,
// LDS-reduces, writes its 64-col record slice with plain stores.
__global__ __launch_bounds__(256) void chunk_kernel(
    const float* __restrict__ wv,
    const int* __restrict__ lens,
    float* __restrict__ ws_sum,
    unsigned char* __restrict__ ws_cnt)
{
    const int cidx = blockIdx.x / 3;  // chunk slot within batch
    const int g    = blockIdx.x % 3;  // colgroup 0..2 (fastest -> co-scheduled)
    const int b    = blockIdx.y;
    const int tid  = threadIdx.x;
    const int lane = tid & 63;
    const int w    = tid >> 6;       // 0..3

    // per-wave redundant scans over the 64 segment lengths
    const int l    = lens[b * NN + lane];
    const int nchl = (l + CHT - 1) >> 7;      // chunks in this segment
    int inclen = l, inch = nchl;
    #pragma unroll
    for (int off = 1; off < 64; off <<= 1) {
        int a = __shfl_up(inclen, off); if (lane >= off) inclen += a;
        int c = __shfl_up(inch,   off); if (lane >= off) inch   += c;
    }
    const int total_ch = __shfl(inch, 63);
    if (cidx >= total_ch) return;             // uniform: whole block exits

    // owning segment: first n with inclusive chunk-scan > cidx
    unsigned long long m = __ballot(inch > cidx);
    const int n         = __ffsll(m) - 1;
    const int seg_len   = __shfl(l, n);
    const int seg_start = __shfl(inclen, n) - seg_len;
    const int ch_base   = __shfl(inch, n) - __shfl(nchl, n);
    const int t0 = seg_start + (cidx - ch_base) * CHT;
    const int t1 = min(seg_start + seg_len, t0 + CHT);

    const int col4 = g * 64 + lane;
    const nfloat4* base = (const nfloat4*)wv + (size_t)b * SS * D4 + col4;

    float4 s = make_float4(0.f, 0.f, 0.f, 0.f);
    float4 c = make_float4(0.f, 0.f, 0.f, 0.f);
    #pragma unroll 8
    for (int t = t0 + w; t < t1; t += 4) {
        nfloat4 v = __builtin_nontemporal_load(base + (size_t)t * D4);
        s.x += v.x; s.y += v.y; s.z += v.z; s.w += v.w;
        c.x += (v.x != 0.f) ? 1.f : 0.f;
        c.y += (v.y != 0.f) ? 1.f : 0.f;
        c.z += (v.z != 0.f) ? 1.f : 0.f;
        c.w += (v.w != 0.f) ? 1.f : 0.f;
    }

    __shared__ float4 s_s[4][64];
    __shared__ float4 s_c[4][64];
    s_s[w][lane] = s;
    s_c[w][lane] = c;
    __syncthreads();

    if (tid < 64) {
        float4 S = make_float4(0.f, 0.f, 0.f, 0.f);
        float4 C = make_float4(0.f, 0.f, 0.f, 0.f);
        #pragma unroll
        for (int j = 0; j < 4; ++j) {
            float4 a = s_s[j][tid], d = s_c[j][tid];
            S.x += a.x; S.y += a.y; S.z += a.z; S.w += a.w;
            C.x += d.x; C.y += d.y; C.z += d.z; C.w += d.w;
        }
        const size_t rec = (size_t)(b * MAXCH + cidx);
        ((float4*)ws_sum)[rec * D4 + g * 64 + tid] = S;
        uchar4 u;                      // chunk counts <= 128, exact in u8
        u.x = (unsigned char)C.x; u.y = (unsigned char)C.y;
        u.z = (unsigned char)C.z; u.w = (unsigned char)C.w;
        ((uchar4*)ws_cnt)[rec * D4 + g * 64 + tid] = u;
    }
}

// ---------------- Phase C: finalize (mean, fallback, rep, masks) -----------
// grid: BB*NN = 512 blocks, 256 threads (192 active cols). Gathers the
// segment's K chunk records, then proven epilogue.
__global__ __launch_bounds__(256) void finalize_kernel(
    const float* __restrict__ wv,
    const int* __restrict__ rep_ids,
    const float* __restrict__ rep_mask,
    const int* __restrict__ lens,
    const float* __restrict__ len_mask,
    const float* __restrict__ ws_sum,
    const unsigned char* __restrict__ ws_cnt,
    float* __restrict__ out)
{
    __shared__ float s_part[4];
    __shared__ int s_info[2];
    const int sgid = blockIdx.x;          // b*NN + n
    const int b = sgid >> 6, n = sgid & 63;
    const int tid = threadIdx.x;
    const int lane = tid & 63;

    if (tid < 64) {                       // wave 0: chunk-base scan
        const int l    = lens[b * NN + tid];
        const int nchl = (l + CHT - 1) >> 7;
        int inch = nchl;
        #pragma unroll
        for (int off = 1; off < 64; off <<= 1) {
            int a = __shfl_up(inch, off); if (lane >= off) inch += a;
        }
        if (tid == n) { s_info[0] = inch - nchl; s_info[1] = nchl; }
    }
    __syncthreads();
    const int ch_base = s_info[0];
    const int K       = s_info[1];
    const bool active = tid < D4;

    float4 S = make_float4(0,0,0,0), C = S;
    if (active) {
        for (int k = 0; k < K; ++k) {
            const size_t rec = (size_t)(b * MAXCH + ch_base + k);
            float4 sv = ((const float4*)ws_sum)[rec * D4 + tid];
            uchar4 cv = ((const uchar4*)ws_cnt)[rec * D4 + tid];
            S.x += sv.x; S.y += sv.y; S.z += sv.z; S.w += sv.w;
            C.x += (float)cv.x; C.y += (float)cv.y;
            C.z += (float)cv.z; C.w += (float)cv.w;
        }
    }

    float tot = C.x + C.y + C.z + C.w;    // 0 for inactive lanes
    #pragma unroll
    for (int off = 32; off; off >>= 1) tot += __shfl_xor(tot, off);
    if ((tid & 63) == 0) s_part[tid >> 6] = tot;
    __syncthreads();
    const float total = s_part[0] + s_part[1] + s_part[2] + s_part[3];

    if (active) {
        float4 mean;
        mean.x = S.x / fmaxf(C.x, 1.f);
        mean.y = S.y / fmaxf(C.y, 1.f);
        mean.z = S.z / fmaxf(C.z, 1.f);
        mean.w = S.w / fmaxf(C.w, 1.f);
        if (total == 0.f) mean = ((const float4*)wv)[tid];   // wv[0,0,:]

        const float lm = len_mask[sgid];
        mean.x *= lm; mean.y *= lm; mean.z *= lm; mean.w *= lm;

        float4* out4 = (float4*)out;
        out4[(size_t)(b * 2 * NN + NN + n) * D4 + tid] = mean;

        const int   rid = rep_ids[sgid];
        const float rm  = rep_mask[sgid];
        float4 rv = ((const float4*)wv)[(size_t)(b * SS + rid) * D4 + tid];
        rv.x *= rm; rv.y *= rm; rv.z *= rm; rv.w *= rm;
        out4[(size_t)(b * 2 * NN + n) * D4 + tid] = rv;

        if (tid == 0) {
            float* masks = out + (size_t)BB * 2 * NN * DD;
            masks[b * 2 * NN + n]      = rm;
            masks[b * 2 * NN + NN + n] = lm;
        }
    }
}

extern "C" void kernel_launch(void* const* d_in, const int* in_sizes, int n_in,
                              void* d_out, int out_size, void* d_ws, size_t ws_size,
                              hipStream_t stream) {
    const float* wv       = (const float*)d_in[0];
    const int*   rep_ids  = (const int*)d_in[1];
    const float* rep_mask = (const float*)d_in[2];
    const int*   lens     = (const int*)d_in[3];
    const float* len_mask = (const float*)d_in[4];
    float*       out      = (float*)d_out;
    float*         ws_sum = (float*)d_ws;
    unsigned char* ws_cnt = (unsigned char*)d_ws + (size_t)NREC * DD * 4;

    dim3 gridB(3 * MAXCH, BB);
    chunk_kernel<<<gridB, 256, 0, stream>>>(wv, lens, ws_sum, ws_cnt);
    finalize_kernel<<<BB * NN, 256, 0, stream>>>(wv, rep_ids, rep_mask, lens,
                                                 len_mask, ws_sum, ws_cnt, out);
}